// Round 4
// baseline (337.133 us; speedup 1.0000x reference)
//
#include <hip/hip_runtime.h>
#include <hip/hip_bf16.h>
#include <stdint.h>

// Swin window-attention block, fully fused per window.
// Grid: 1536 blocks, 512 threads (8 waves). 2 blocks/CU (LDS 78.8 KiB).
// R3 (resubmit — prior round hit GPU acquisition timeout, never measured):
// ILP restructure — merged Q+KV compute phase (5 barriers total),
// distance-2 register-pipelined weight streams, early issue of loads
// across barriers. Layouts identical to R2 (which passed).

#define NTOK 64
#define CDIM 192
#define NHEAD 6
#define NWIN 192
#define LDX 200   // bf16 stride for token-major tiles (192 + 8 pad)
#define LDV 72    // bf16 stride for Vt (64 + 8 pad)

typedef short bf16x8 __attribute__((ext_vector_type(8)));
typedef short short4v __attribute__((ext_vector_type(4)));
typedef float f32x4 __attribute__((ext_vector_type(4)));
typedef int   i32x4 __attribute__((ext_vector_type(4)));

#define MFMA __builtin_amdgcn_mfma_f32_16x16x32_bf16

static __device__ __forceinline__ short f2bf(float f) {
    uint32_t u = __float_as_uint(f);
    u += 0x7fffu + ((u >> 16) & 1u);   // RNE
    return (short)(u >> 16);
}
static __device__ __forceinline__ int pack2bf(float lo, float hi) {
    return ((int)(unsigned short)f2bf(hi) << 16) | (int)(unsigned short)f2bf(lo);
}

// ---- prep: weights f32->bf16, bias table gather ----
__global__ void prep_kernel(const float* __restrict__ wq, const float* __restrict__ wkv,
                            const float* __restrict__ wp, const int* __restrict__ rpi,
                            const float* __restrict__ rpb,
                            short* __restrict__ wq_b, short* __restrict__ wkv_b,
                            short* __restrict__ wp_b, float* __restrict__ bias)
{
    int gid = blockIdx.x * 256 + threadIdx.x;   // 0..36863 (float4 units)
    const float4* src; short4v* dst; int idx;
    if (gid < 9216)       { src = (const float4*)wq;  dst = (short4v*)wq_b;  idx = gid; }
    else if (gid < 27648) { src = (const float4*)wkv; dst = (short4v*)wkv_b; idx = gid - 9216; }
    else                  { src = (const float4*)wp;  dst = (short4v*)wp_b;  idx = gid - 27648; }
    float4 v = src[idx];
    short4v o; o[0]=f2bf(v.x); o[1]=f2bf(v.y); o[2]=f2bf(v.z); o[3]=f2bf(v.w);
    dst[idx] = o;
    if (gid < 24576) {  // bias[h][n][m] = rpb_table[rpi[n][m]][h]
        int h = gid >> 12, nm = gid & 4095;
        bias[gid] = rpb[rpi[nm] * NHEAD + h];
    }
}

__global__ void __launch_bounds__(512, 4)
swin_fused(const float* __restrict__ x, const float* __restrict__ px,
           const float* __restrict__ mask, const float* __restrict__ biasT,
           const short* __restrict__ wq_b, const short* __restrict__ wkv_b,
           const short* __restrict__ wp_b,
           const float* __restrict__ bq, const float* __restrict__ bkv,
           const float* __restrict__ bp, float* __restrict__ out)
{
    extern __shared__ char smem[];
    short* Bx = (short*)smem;                 // [64][LDX]  X -> Q -> O
    short* Bp = Bx + 64 * LDX;                // [64][LDX]  Px -> K
    short* Vt = Bp + 64 * LDX;                // [192][LDV] V transposed

    const int tid = threadIdx.x;
    const int wv  = tid >> 6;    // wave 0..7
    const int ln  = tid & 63;
    const int lc  = ln & 15;     // MFMA lane col
    const int lg  = ln >> 4;     // lane group 0..3
    const int b_  = blockIdx.x;
    const int win = b_ % NWIN;

    const f32x4 zf = {0.f, 0.f, 0.f, 0.f};

    const int mtq  = wv >> 1;          // Q/O row tile (rows mtq*16..+16)
    const int cbq  = (wv & 1) * 96;    // Q/O col half
    const int cbkv = wv * 48;          // KV output-channel base

    const short* wqbase = wq_b  + (size_t)(cbq  + lc) * CDIM + lg * 8;
    const short* wkbase = wkv_b + (size_t)(cbkv + lc) * CDIM + lg * 8;

    // ---- early weight preloads (independent of LDS; hide under stage) ----
    bf16x8 qcA0 = *(const bf16x8*)(wqbase + 0 * 16 * CDIM);            // Q unit 0 (kk0, ct 0..2)
    bf16x8 qcA1 = *(const bf16x8*)(wqbase + 1 * 16 * CDIM);
    bf16x8 qcA2 = *(const bf16x8*)(wqbase + 2 * 16 * CDIM);
    bf16x8 qcB0 = *(const bf16x8*)(wqbase + 3 * 16 * CDIM);            // Q unit 1 (kk0, ct 3..5)
    bf16x8 qcB1 = *(const bf16x8*)(wqbase + 4 * 16 * CDIM);
    bf16x8 qcB2 = *(const bf16x8*)(wqbase + 5 * 16 * CDIM);
    bf16x8 kc0  = *(const bf16x8*)(wkbase + 0 * 16 * CDIM);            // KV unit 0 (kk0)
    bf16x8 kc1  = *(const bf16x8*)(wkbase + 1 * 16 * CDIM);
    bf16x8 kc2  = *(const bf16x8*)(wkbase + 2 * 16 * CDIM);

    // ---------- stage x, px -> LDS bf16 ----------
    {
        const float4* xs = (const float4*)(x  + (size_t)b_ * (NTOK * CDIM));
        const float4* ps = (const float4*)(px + (size_t)b_ * (NTOK * CDIM));
        #pragma unroll
        for (int i = 0; i < 6; ++i) {
            int f = tid + 512 * i;           // 0..3071 float4s
            int row = f / 48, col = (f - row * 48) * 4;
            float4 v = xs[f];
            float4 w = ps[f];
            short4v a; a[0]=f2bf(v.x); a[1]=f2bf(v.y); a[2]=f2bf(v.z); a[3]=f2bf(v.w);
            short4v b; b[0]=f2bf(w.x); b[1]=f2bf(w.y); b[2]=f2bf(w.z); b[3]=f2bf(w.w);
            *(short4v*)(&Bx[row * LDX + col]) = a;
            *(short4v*)(&Bp[row * LDX + col]) = b;
        }
    }
    __syncthreads();

    // ---------- Q compute: Bx(64x192) @ wq^T -> regs (12 units, dist-2) ----------
    f32x4 aq[6];
    #pragma unroll
    for (int i = 0; i < 6; ++i) aq[i] = zf;
    {
        bf16x8 c0 = qcA0, c1 = qcA1, c2 = qcA2;          // unit u
        bf16x8 n0 = qcB0, n1 = qcB1, n2 = qcB2;          // unit u+1
        bf16x8 m0, m1, m2;                               // unit u+2
        bf16x8 qa = *(const bf16x8*)(&Bx[(mtq * 16 + lc) * LDX + lg * 8]);
        #pragma unroll
        for (int u = 0; u < 12; ++u) {
            const int kk = u >> 1, half = u & 1;
            if (u + 2 < 12) {
                const int k2 = (u + 2) >> 1, h2 = (u + 2) & 1;
                const short* wn = wqbase + h2 * (3 * 16 * CDIM) + k2 * 32;
                m0 = *(const bf16x8*)(wn + 0 * 16 * CDIM);
                m1 = *(const bf16x8*)(wn + 1 * 16 * CDIM);
                m2 = *(const bf16x8*)(wn + 2 * 16 * CDIM);
            }
            aq[half * 3 + 0] = MFMA(qa, c0, aq[half * 3 + 0], 0, 0, 0);
            aq[half * 3 + 1] = MFMA(qa, c1, aq[half * 3 + 1], 0, 0, 0);
            aq[half * 3 + 2] = MFMA(qa, c2, aq[half * 3 + 2], 0, 0, 0);
            if (half == 1 && kk < 5)
                qa = *(const bf16x8*)(&Bx[(mtq * 16 + lc) * LDX + (kk + 1) * 32 + lg * 8]);
            c0 = n0; c1 = n1; c2 = n2;
            n0 = m0; n1 = m1; n2 = m2;
        }
    }

    // ---------- KV compute: Bp(64x192) @ wkv^T -> regs (6 units, dist-1) ----------
    f32x4 akv[4][3];
    #pragma unroll
    for (int mt = 0; mt < 4; ++mt)
        #pragma unroll
        for (int ct = 0; ct < 3; ++ct) akv[mt][ct] = zf;
    {
        bf16x8 c0 = kc0, c1 = kc1, c2 = kc2;
        bf16x8 n0, n1, n2;
        #pragma unroll
        for (int kk = 0; kk < 6; ++kk) {
            if (kk + 1 < 6) {
                const short* wn = wkbase + (kk + 1) * 32;
                n0 = *(const bf16x8*)(wn + 0 * 16 * CDIM);
                n1 = *(const bf16x8*)(wn + 1 * 16 * CDIM);
                n2 = *(const bf16x8*)(wn + 2 * 16 * CDIM);
            }
            bf16x8 afr[4];
            #pragma unroll
            for (int mt = 0; mt < 4; ++mt)
                afr[mt] = *(const bf16x8*)(&Bp[(mt * 16 + lc) * LDX + kk * 32 + lg * 8]);
            #pragma unroll
            for (int mt = 0; mt < 4; ++mt) {
                akv[mt][0] = MFMA(afr[mt], c0, akv[mt][0], 0, 0, 0);
                akv[mt][1] = MFMA(afr[mt], c1, akv[mt][1], 0, 0, 0);
                akv[mt][2] = MFMA(afr[mt], c2, akv[mt][2], 0, 0, 0);
            }
            c0 = n0; c1 = n1; c2 = n2;
        }
    }

    // ---- hoist mask loads (global, independent of LDS writes below) ----
    const int rt = mtq * 16;
    const int hb = (wv & 1) * 3;
    float4 mask4[4];
    {
        const float* mrow = mask + (size_t)win * 4096 + (rt + lc) * 64 + lg * 4;
        #pragma unroll
        for (int t = 0; t < 4; ++t) mask4[t] = *(const float4*)(mrow + t * 16);
    }

    __syncthreads();   // all reads of Bx(X), Bp(Px) done

    // ---------- write phase: K -> Bp, V -> Vt, Q -> Bx ----------
    if (wv < 4) {      // K channels cbkv..+48 -> Bp row-major
        #pragma unroll
        for (int ct = 0; ct < 3; ++ct) {
            const int ch = cbkv + ct * 16 + lc;
            const float bb = bkv[ch];
            #pragma unroll
            for (int mt = 0; mt < 4; ++mt)
                #pragma unroll
                for (int j = 0; j < 4; ++j)
                    Bp[(mt * 16 + lg * 4 + j) * LDX + ch] = f2bf(akv[mt][ct][j] + bb);
        }
    } else {           // V channels -> Vt transposed [ch][token], b64 writes
        const int vb = cbkv - 192;
        #pragma unroll
        for (int ct = 0; ct < 3; ++ct) {
            const int vch = vb + ct * 16 + lc;
            const float bb = bkv[192 + vch];
            #pragma unroll
            for (int mt = 0; mt < 4; ++mt) {
                short4v o;
                #pragma unroll
                for (int j = 0; j < 4; ++j) o[j] = f2bf(akv[mt][ct][j] + bb);
                *(short4v*)(&Vt[vch * LDV + mt * 16 + lg * 4]) = o;
            }
        }
    }
    #pragma unroll
    for (int ct = 0; ct < 6; ++ct) {   // Q -> Bx rows mtq*16..+16, cols cbq..+96
        const int ch = cbq + ct * 16 + lc;
        const float bb = bq[ch];
        #pragma unroll
        for (int j = 0; j < 4; ++j)
            Bx[(rt + lg * 4 + j) * LDX + ch] = f2bf(aq[ct][j] + bb);
    }
    __syncthreads();

    // ---------- attention: wave owns q-rows [rt,rt+16) x heads [hb,hb+3) ----------
    // Swapped QK^T: st[t] = mfma(K_t, Q) -> lane (lg,lc) holds
    // S[q=rt+lc][k=t*16+lg*4+j]. Softmax reduces over lg bits (xor 16,32).
    f32x4 oacc[6];
    #pragma unroll
    for (int i = 0; i < 6; ++i) oacc[i] = zf;
    const int hi = lg >> 1;                    // tile-select bit for P relayout
    const int sA = ((lg & 1) * 2) * 16 + lc;   // shfl source lanes
    const int sB = sA + 16;
    const float scale = 0.17677669529663687f;  // 32^-0.5

    #pragma unroll
    for (int hh = 0; hh < 3; ++hh) {
        const int h = hb + hh;
        // bias loads issued first (L2), consumed after QK^T
        const float* brow = biasT + h * 4096 + (rt + lc) * 64 + lg * 4;
        float4 b40 = *(const float4*)(brow);
        float4 b41 = *(const float4*)(brow + 16);
        float4 b42 = *(const float4*)(brow + 32);
        float4 b43 = *(const float4*)(brow + 48);
        bf16x8 bQ = *(const bf16x8*)(&Bx[(rt + lc) * LDX + h * 32 + lg * 8]);
        f32x4 st[4];
        #pragma unroll
        for (int t = 0; t < 4; ++t) {
            bf16x8 aK = *(const bf16x8*)(&Bp[(t * 16 + lc) * LDX + h * 32 + lg * 8]);
            st[t] = MFMA(aK, bQ, zf, 0, 0, 0);
        }
        float p[4][4];
        float mx = -3.0e38f;
        float4 b4a[4] = {b40, b41, b42, b43};
        #pragma unroll
        for (int t = 0; t < 4; ++t) {
            p[t][0] = st[t][0] * scale + b4a[t].x + mask4[t].x;
            p[t][1] = st[t][1] * scale + b4a[t].y + mask4[t].y;
            p[t][2] = st[t][2] * scale + b4a[t].z + mask4[t].z;
            p[t][3] = st[t][3] * scale + b4a[t].w + mask4[t].w;
            mx = fmaxf(mx, fmaxf(fmaxf(p[t][0], p[t][1]), fmaxf(p[t][2], p[t][3])));
        }
        mx = fmaxf(mx, __shfl_xor(mx, 16, 64));
        mx = fmaxf(mx, __shfl_xor(mx, 32, 64));
        float sm = 0.f;
        #pragma unroll
        for (int t = 0; t < 4; ++t) {
            p[t][0] = __expf(p[t][0] - mx);
            p[t][1] = __expf(p[t][1] - mx);
            p[t][2] = __expf(p[t][2] - mx);
            p[t][3] = __expf(p[t][3] - mx);
            sm += (p[t][0] + p[t][1]) + (p[t][2] + p[t][3]);
        }
        sm += __shfl_xor(sm, 16, 64);
        sm += __shfl_xor(sm, 32, 64);
        const float inv = 1.0f / sm;
        int pk[4][2];
        #pragma unroll
        for (int t = 0; t < 4; ++t) {
            pk[t][0] = pack2bf(p[t][0] * inv, p[t][1] * inv);
            pk[t][1] = pack2bf(p[t][2] * inv, p[t][3] * inv);
        }
        // P relayout: dest lane (lg,lc) A-frag <- pk[2ks+hi][*] of lanes sA/sB
        #pragma unroll
        for (int ks = 0; ks < 2; ++ks) {
            const int t0 = ks * 2, t1 = ks * 2 + 1;
            int u0a = __shfl(pk[t0][0], sA, 64), u0b = __shfl(pk[t1][0], sA, 64);
            int u1a = __shfl(pk[t0][1], sA, 64), u1b = __shfl(pk[t1][1], sA, 64);
            int u2a = __shfl(pk[t0][0], sB, 64), u2b = __shfl(pk[t1][0], sB, 64);
            int u3a = __shfl(pk[t0][1], sB, 64), u3b = __shfl(pk[t1][1], sB, 64);
            i32x4 wi;
            wi[0] = hi ? u0b : u0a;
            wi[1] = hi ? u1b : u1a;
            wi[2] = hi ? u2b : u2a;
            wi[3] = hi ? u3b : u3a;
            bf16x8 pf = __builtin_bit_cast(bf16x8, wi);
            #pragma unroll
            for (int t2 = 0; t2 < 2; ++t2) {
                bf16x8 vf = *(const bf16x8*)(&Vt[(h * 32 + t2 * 16 + lc) * LDV + ks * 32 + lg * 8]);
                oacc[hh * 2 + t2] = MFMA(pf, vf, oacc[hh * 2 + t2], 0, 0, 0);
            }
        }
    }
    __syncthreads();   // all waves done reading Qs(Bx)

    // ---------- O -> Bx (bf16, row-major) + early wp preloads ----------
    #pragma unroll
    for (int hh = 0; hh < 3; ++hh)
        #pragma unroll
        for (int t2 = 0; t2 < 2; ++t2) {
            const int col = (hb + hh) * 32 + t2 * 16 + lc;
            #pragma unroll
            for (int j = 0; j < 4; ++j)
                Bx[(rt + lg * 4 + j) * LDX + col] = f2bf(oacc[hh * 2 + t2][j]);
        }
    const short* wpbase = wp_b + (size_t)(cbq + lc) * CDIM + lg * 8;
    bf16x8 pcA0 = *(const bf16x8*)(wpbase + 0 * 16 * CDIM);
    bf16x8 pcA1 = *(const bf16x8*)(wpbase + 1 * 16 * CDIM);
    bf16x8 pcA2 = *(const bf16x8*)(wpbase + 2 * 16 * CDIM);
    bf16x8 pcB0 = *(const bf16x8*)(wpbase + 3 * 16 * CDIM);
    bf16x8 pcB1 = *(const bf16x8*)(wpbase + 4 * 16 * CDIM);
    bf16x8 pcB2 = *(const bf16x8*)(wpbase + 5 * 16 * CDIM);
    __syncthreads();

    // ---------- out projection: Bx(64x192) @ wp^T + bp -> global (dist-2) ----------
    {
        f32x4 acc[6];
        #pragma unroll
        for (int i = 0; i < 6; ++i) acc[i] = zf;
        bf16x8 c0 = pcA0, c1 = pcA1, c2 = pcA2;
        bf16x8 n0 = pcB0, n1 = pcB1, n2 = pcB2;
        bf16x8 m0, m1, m2;
        bf16x8 oa = *(const bf16x8*)(&Bx[(rt + lc) * LDX + lg * 8]);
        #pragma unroll
        for (int u = 0; u < 12; ++u) {
            const int kk = u >> 1, half = u & 1;
            if (u + 2 < 12) {
                const int k2 = (u + 2) >> 1, h2 = (u + 2) & 1;
                const short* wn = wpbase + h2 * (3 * 16 * CDIM) + k2 * 32;
                m0 = *(const bf16x8*)(wn + 0 * 16 * CDIM);
                m1 = *(const bf16x8*)(wn + 1 * 16 * CDIM);
                m2 = *(const bf16x8*)(wn + 2 * 16 * CDIM);
            }
            acc[half * 3 + 0] = MFMA(oa, c0, acc[half * 3 + 0], 0, 0, 0);
            acc[half * 3 + 1] = MFMA(oa, c1, acc[half * 3 + 1], 0, 0, 0);
            acc[half * 3 + 2] = MFMA(oa, c2, acc[half * 3 + 2], 0, 0, 0);
            if (half == 1 && kk < 5)
                oa = *(const bf16x8*)(&Bx[(rt + lc) * LDX + (kk + 1) * 32 + lg * 8]);
            c0 = n0; c1 = n1; c2 = n2;
            n0 = m0; n1 = m1; n2 = m2;
        }
        float* orow = out + (size_t)b_ * (NTOK * CDIM);
        #pragma unroll
        for (int ct = 0; ct < 6; ++ct) {
            const int ch = cbq + ct * 16 + lc;
            const float bb = bp[ch];
            #pragma unroll
            for (int j = 0; j < 4; ++j)
                orow[(rt + lg * 4 + j) * CDIM + ch] = acc[ct][j] + bb;
        }
    }
}

extern "C" void kernel_launch(void* const* d_in, const int* in_sizes, int n_in,
                              void* d_out, int out_size, void* d_ws, size_t ws_size,
                              hipStream_t stream) {
    const float* x    = (const float*)d_in[0];
    const float* px   = (const float*)d_in[1];
    const float* mask = (const float*)d_in[2];
    const int*   rpi  = (const int*)d_in[3];
    const float* rpb  = (const float*)d_in[4];
    const float* wq   = (const float*)d_in[5];
    const float* bq   = (const float*)d_in[6];
    const float* wkv  = (const float*)d_in[7];
    const float* bkv  = (const float*)d_in[8];
    const float* wp   = (const float*)d_in[9];
    const float* bp   = (const float*)d_in[10];
    float* out = (float*)d_out;

    char* ws = (char*)d_ws;
    short* wq_b  = (short*)ws;                          // 73728 B
    short* wkv_b = (short*)(ws + 73728);                // 147456 B
    short* wp_b  = (short*)(ws + 73728 + 147456);       // 73728 B
    float* bias  = (float*)(ws + 73728 + 147456 + 73728); // 98304 B

    prep_kernel<<<144, 256, 0, stream>>>(wq, wkv, wp, rpi, rpb, wq_b, wkv_b, wp_b, bias);

    const int lds_bytes = (64 * LDX + 64 * LDX + 192 * LDV) * 2;   // 78848
    hipFuncSetAttribute((const void*)swin_fused, hipFuncAttributeMaxDynamicSharedMemorySize, lds_bytes);
    swin_fused<<<1536, 512, lds_bytes, stream>>>(x, px, mask, bias, wq_b, wkv_b, wp_b,
                                                 bq, bkv, bp, out);
}